// Round 8
// baseline (346.032 us; speedup 1.0000x reference)
//
#include <hip/hip_runtime.h>

#define N_NODES 50000
#define N_EDGES 800000
#define M_IDX   25000
#define DMAX    64   // Poisson(16) degree; P(deg>=64) ~ 1e-19 -- safe pad

typedef float v2f __attribute__((ext_vector_type(2)));

// ---------------------------------------------------------------------------
// Prep (once): scatter per-edge record {pos[t]-pos[s], src-bits} into the
// destination node's packed row pdata[t*DMAX+p]. Two independent edges per
// thread. Blocks 0-2 additionally fold Linear+BN into wtab:
// wtab[l*256 + i*16+o] = {W0,W1,W2,B}.
// ---------------------------------------------------------------------------
__global__ __launch_bounds__(256) void prep_kernel(
    const int*   __restrict__ ei,     // [2,E]
    const float* __restrict__ pos,    // [N,3]
    int*         __restrict__ cnt,    // [N] (pre-zeroed)
    float4*      __restrict__ pdata,  // [N,DMAX] xyz = pseudo, w = src bits
    const float* __restrict__ lw0, const float* __restrict__ lb0,
    const float* __restrict__ g0,  const float* __restrict__ b0,
    const float* __restrict__ lw1, const float* __restrict__ lb1,
    const float* __restrict__ g1,  const float* __restrict__ b1,
    const float* __restrict__ lw2, const float* __restrict__ lb2,
    const float* __restrict__ g2,  const float* __restrict__ b2,
    float4*      __restrict__ wtab,   // [3*256]
    int E)
{
    if (blockIdx.x < 3) {
        const int l = blockIdx.x, j = threadIdx.x;
        const float *lw, *lb, *gm, *bt; int d;
        if (l == 0)      { lw = lw0; lb = lb0; gm = g0; bt = b0; d = 128; }
        else if (l == 1) { lw = lw1; lb = lb1; gm = g1; bt = b1; d = 256; }
        else             { lw = lw2; lb = lb2; gm = g2; bt = b2; d = 256; }
        if (j < d) {
            const float g = gm[j];
            float4 w4;
            w4.x = lw[j] * g;
            w4.y = lw[d + j] * g;
            w4.z = lw[2 * d + j] * g;
            w4.w = fmaf(lb[j], g, bt[j]);
            wtab[l * 256 + j] = w4;
        }
    }

    const int e0 = blockIdx.x * 512 + threadIdx.x;
    const int e1 = e0 + 256;
    const bool v0 = e0 < E, v1 = e1 < E;
    int t0 = 0, s0 = 0, t1 = 0, s1 = 0;
    if (v0) { t0 = ei[E + e0]; s0 = ei[e0]; }
    if (v1) { t1 = ei[E + e1]; s1 = ei[e1]; }
    int p0 = 0, p1 = 0;
    if (v0) p0 = atomicAdd(&cnt[t0], 1);
    if (v1) p1 = atomicAdd(&cnt[t1], 1);
    if (v0) {
        float4 pd;
        pd.x = pos[t0 * 3 + 0] - pos[s0 * 3 + 0];
        pd.y = pos[t0 * 3 + 1] - pos[s0 * 3 + 1];
        pd.z = pos[t0 * 3 + 2] - pos[s0 * 3 + 2];
        pd.w = __int_as_float(s0);
        if (p0 < DMAX) pdata[(size_t)t0 * DMAX + p0] = pd;
    }
    if (v1) {
        float4 pd;
        pd.x = pos[t1 * 3 + 0] - pos[s1 * 3 + 0];
        pd.y = pos[t1 * 3 + 1] - pos[s1 * 3 + 1];
        pd.z = pos[t1 * 3 + 2] - pos[s1 * 3 + 2];
        pd.w = __int_as_float(s1);
        if (p1 < DMAX) pdata[(size_t)t1 * DMAX + p1] = pd;
    }
}

// load NF4 float4s (one half-row of h) as v2f pairs
template<int NF4>
__device__ __forceinline__ void load_half(const float4* __restrict__ h4,
                                          size_t base, v2f* xv) {
#pragma unroll
    for (int k = 0; k < NF4; ++k) {
        float4 v = h4[base + k];
        xv[2 * k]     = (v2f){v.x, v.y};
        xv[2 * k + 1] = (v2f){v.z, v.w};
    }
}

// ---------------------------------------------------------------------------
// Fused layer, persistent waves, TWO NODES PER WAVE (lane partition):
// lane = g*16+o; g>>1 selects node (2tb / 2tb+1), g&1 selects the input-
// channel HALF (IQ = CI/2 channels per lane). Doubles independent gather
// chains per wave (stall fix for R7's 55% latency stall) and halves
// per-edge overhead (amortized over a 2x longer packed MLP chain).
// Divergent per-node loop bounds are handled by exec masking. Reduction:
// one shfl_xor(16) pairs g0<->g1 (node A) and g2<->g3 (node B); even-g
// lanes store.
// ---------------------------------------------------------------------------
template<int CI>
__global__ __launch_bounds__(256) void node_wave_kernel(
    const float4* __restrict__ pdata,  // [N,DMAX]
    const int*    __restrict__ cnt,    // [N]
    const float*  __restrict__ h_in,   // [N,CI]
    const float4* __restrict__ wt_l,   // [CI*16] prefolded {W0,W1,W2,B}
    const float*  __restrict__ root,   // [CI,16]
    const float*  __restrict__ bias,   // [16]
    float*        __restrict__ h_out,  // [N,16]
    int N)
{
    constexpr int IQ  = CI / 2;        // input channels per lane
    constexpr int NP  = IQ / 2;        // v2f pairs per lane
    constexpr int F4  = CI / 4;        // float4s per h row
    constexpr int NF4 = IQ / 4;        // float4s per half-row
    const int gtid   = blockIdx.x * blockDim.x + threadIdx.x;
    const int wid    = gtid >> 6;
    const int nwaves = (gridDim.x * blockDim.x) >> 6;
    const int lane   = gtid & 63;
    const int g      = lane >> 4;      // group 0..3
    const int o      = lane & 15;      // out channel
    const int nsel   = g >> 1;         // node select within pair
    const int ih     = g & 1;          // input-channel half

    // ---- hoisted per-lane constants (node-loop invariant) ----
    v2f W0[NP], W1[NP], W2[NP], Bv[NP], Rv[NP];
#pragma unroll
    for (int u = 0; u < NP; ++u) {
        float4 wa = wt_l[(ih * IQ + 2 * u) * 16 + o];
        float4 wb = wt_l[(ih * IQ + 2 * u + 1) * 16 + o];
        W0[u] = (v2f){wa.x, wb.x};
        W1[u] = (v2f){wa.y, wb.y};
        W2[u] = (v2f){wa.z, wb.z};
        Bv[u] = (v2f){wa.w, wb.w};
        Rv[u] = (v2f){root[(ih * IQ + 2 * u) * 16 + o],
                      root[(ih * IQ + 2 * u + 1) * 16 + o]};
    }
    const float bo = bias[o];
    const v2f zero = 0.f;
    const float4* __restrict__ h4 = (const float4*)h_in;

    const int NPAIR = N >> 1;
    for (int tb = wid; tb < NPAIR; tb += nwaves) {
        const int t   = 2 * tb + nsel;
        const int deg = cnt[t];
        const int dl  = min(deg, DMAX);
        const float4* __restrict__ row = pdata + (size_t)t * DMAX;

        v2f vacc = 0.f;
        for (int p = 0; p < dl; p += 2) {
            float4 pdA = row[p];
            const bool okB = (p + 1) < dl;
            float4 pdB = row[okB ? p + 1 : p];
            const int sA = __float_as_int(pdA.w);
            const int sB = __float_as_int(pdB.w);
            v2f xA[NP], xB[NP];
            load_half<NF4>(h4, (size_t)sA * F4 + ih * NF4, xA);
            load_half<NF4>(h4, (size_t)sB * F4 + ih * NF4, xB);
            v2f ax = pdA.x, ay = pdA.y, az = pdA.z;
            v2f bx = pdB.x, by = pdB.y, bz = pdB.z;
            v2f eA = 0.f, eB = 0.f;
#pragma unroll
            for (int u = 0; u < NP; ++u) {
                v2f wA = __builtin_elementwise_fma(az, W2[u],
                         __builtin_elementwise_fma(ay, W1[u],
                         __builtin_elementwise_fma(ax, W0[u], Bv[u])));
                wA = __builtin_elementwise_max(wA, zero);
                eA = __builtin_elementwise_fma(xA[u], wA, eA);
                v2f wB = __builtin_elementwise_fma(bz, W2[u],
                         __builtin_elementwise_fma(by, W1[u],
                         __builtin_elementwise_fma(bx, W0[u], Bv[u])));
                wB = __builtin_elementwise_max(wB, zero);
                eB = __builtin_elementwise_fma(xB[u], wB, eB);
            }
            vacc += eA + (okB ? eB : zero);
        }
        float acc = vacc.x + vacc.y;

        // root partial for this lane's channel half
        v2f xT[NP];
        load_half<NF4>(h4, (size_t)t * F4 + ih * NF4, xT);
        v2f rpv = 0.f;
#pragma unroll
        for (int u = 0; u < NP; ++u)
            rpv = __builtin_elementwise_fma(xT[u], Rv[u], rpv);
        float rp = rpv.x + rpv.y;

        // combine the two channel halves of each node (g0<->g1, g2<->g3)
        float contrib = fmaf(acc, 1.0f / fmaxf((float)deg, 1.0f), rp);
        contrib += __shfl_xor(contrib, 16);

        if ((g & 1) == 0) h_out[t * 16 + o] = fmaxf(contrib + bo, 0.f);
    }
}

// ---------------------------------------------------------------------------
// Output gather: out = [h[idx] (M*16) | pos[idx] (M*3) | batch[idx] (M)]
// ---------------------------------------------------------------------------
__global__ __launch_bounds__(256) void gather_kernel(
    const float* __restrict__ h,
    const float* __restrict__ pos,
    const int*   __restrict__ batch,
    const int*   __restrict__ idx,
    float*       __restrict__ out,
    int M)
{
    int j = blockIdx.x * blockDim.x + threadIdx.x;
    if (j >= M) return;
    int n = idx[j];
    float4*       o4 = (float4*)out + (size_t)j * 4;
    const float4* h4 = (const float4*)(h + (size_t)n * 16);
    o4[0] = h4[0]; o4[1] = h4[1]; o4[2] = h4[2]; o4[3] = h4[3];
    float* po = out + (size_t)M * 16 + (size_t)j * 3;
    po[0] = pos[n * 3 + 0];
    po[1] = pos[n * 3 + 1];
    po[2] = pos[n * 3 + 2];
    ((int*)out)[(size_t)M * 19 + j] = batch[n];
}

extern "C" void kernel_launch(void* const* d_in, const int* in_sizes, int n_in,
                              void* d_out, int out_size, void* d_ws, size_t ws_size,
                              hipStream_t stream) {
    const float* x      = (const float*)d_in[0];
    const float* pos    = (const float*)d_in[1];
    const float* lin_w0 = (const float*)d_in[2];
    const float* lin_b0 = (const float*)d_in[3];
    const float* gamma0 = (const float*)d_in[4];
    const float* beta0  = (const float*)d_in[5];
    const float* root0  = (const float*)d_in[6];
    const float* bias0  = (const float*)d_in[7];
    const float* lin_w1 = (const float*)d_in[8];
    const float* lin_b1 = (const float*)d_in[9];
    const float* gamma1 = (const float*)d_in[10];
    const float* beta1  = (const float*)d_in[11];
    const float* root1  = (const float*)d_in[12];
    const float* bias1  = (const float*)d_in[13];
    const float* lin_w2 = (const float*)d_in[14];
    const float* lin_b2 = (const float*)d_in[15];
    const float* gamma2 = (const float*)d_in[16];
    const float* beta2  = (const float*)d_in[17];
    const float* root2  = (const float*)d_in[18];
    const float* bias2  = (const float*)d_in[19];
    const int*   batch  = (const int*)d_in[20];
    const int*   idx    = (const int*)d_in[21];
    const int*   ei     = (const int*)d_in[22];
    float*       out    = (float*)d_out;

    // workspace layout (all 16B aligned)
    float4* pdata = (float4*)d_ws;                                // N*DMAX float4 (51.2 MB)
    float*  hA    = (float*)(pdata + (size_t)N_NODES * DMAX);     // N*16 floats
    float*  hB    = hA + (size_t)N_NODES * 16;                    // N*16 floats
    int*    cnt   = (int*)(hB + (size_t)N_NODES * 16);            // N ints
    float4* wtab  = (float4*)(cnt + N_NODES);                     // 3*256 float4 (12 KB)

    hipMemsetAsync(cnt, 0, N_NODES * sizeof(int), stream);
    prep_kernel<<<(N_EDGES + 511) / 512, 256, 0, stream>>>(
        ei, pos, cnt, pdata,
        lin_w0, lin_b0, gamma0, beta0,
        lin_w1, lin_b1, gamma1, beta1,
        lin_w2, lin_b2, gamma2, beta2, wtab, N_EDGES);

    const int NB = 2048;   // 8192 persistent waves

    node_wave_kernel<8><<<NB, 256, 0, stream>>>(pdata, cnt, x,
        wtab, root0, bias0, hA, N_NODES);
    node_wave_kernel<16><<<NB, 256, 0, stream>>>(pdata, cnt, hA,
        wtab + 256, root1, bias1, hB, N_NODES);
    node_wave_kernel<16><<<NB, 256, 0, stream>>>(pdata, cnt, hB,
        wtab + 512, root2, bias2, hA, N_NODES);

    gather_kernel<<<(M_IDX + 255) / 256, 256, 0, stream>>>(hA, pos, batch, idx, out, M_IDX);
}